// Round 1
// baseline (167.323 us; speedup 1.0000x reference)
//
#include <hip/hip_runtime.h>

#define S_LEN 4096
#define DH 64
#define SPAN 512

typedef _Float16 f16x8 __attribute__((ext_vector_type(8)));
typedef float f32x4 __attribute__((ext_vector_type(4)));

#define MFMA16 __builtin_amdgcn_mfma_f32_16x16x32_f16

__device__ __forceinline__ f16x8 load_cvt8(const float* __restrict__ p) {
  float4 a = *(const float4*)p;
  float4 b = *(const float4*)(p + 4);
  f16x8 r;
  r[0] = (_Float16)a.x; r[1] = (_Float16)a.y; r[2] = (_Float16)a.z; r[3] = (_Float16)a.w;
  r[4] = (_Float16)b.x; r[5] = (_Float16)b.y; r[6] = (_Float16)b.z; r[7] = (_Float16)b.w;
  return r;
}

// MODE: 0 = no mask (history), 1 = causal diag, 2 = spatial diag
template<int MODE>
__device__ __forceinline__ void kv_tile(
    const float* __restrict__ Kh, const float* __restrict__ Vh,
    int kt, int qg_row, int c, int g,
    const f16x8 (&qf)[2], float& m_run, float& l_run, f32x4 (&of)[4])
{
  // K fragments: A-operand of S^T = K * Q^T.  A[m=c (local kv)][k=8g+j (d)]
  f16x8 kf0a = load_cvt8(Kh + (kt +      c) * DH + 8 * g);
  f16x8 kf0b = load_cvt8(Kh + (kt +      c) * DH + 8 * g + 32);
  f16x8 kf1a = load_cvt8(Kh + (kt + 16 + c) * DH + 8 * g);
  f16x8 kf1b = load_cvt8(Kh + (kt + 16 + c) * DH + 8 * g + 32);

  f32x4 st0 = {0.f, 0.f, 0.f, 0.f};
  f32x4 st1 = {0.f, 0.f, 0.f, 0.f};
  st0 = MFMA16(kf0a, qf[0], st0, 0, 0, 0);
  st0 = MFMA16(kf0b, qf[1], st0, 0, 0, 0);
  st1 = MFMA16(kf1a, qf[0], st1, 0, 0, 0);
  st1 = MFMA16(kf1b, qf[1], st1, 0, 0, 0);
  // acc layout: S^T[kv = kt + 16t + 4g + r][q = qbase + c]

  const float SCL = 0.18033688011112042f;  // (1/sqrt(64)) * log2(e)
  float ss[8];
  #pragma unroll
  for (int t = 0; t < 2; ++t) {
    #pragma unroll
    for (int r = 0; r < 4; ++r) {
      float vsc = (t ? st1[r] : st0[r]) * SCL;
      if (MODE == 1) {
        int kv = kt + 16 * t + 4 * g + r;
        vsc = (kv <= qg_row) ? vsc : -1e30f;
      } else if (MODE == 2) {
        int kv = kt + 16 * t + 4 * g + r;
        int pq = qg_row & (SPAN - 1), pk = kv & (SPAN - 1);
        int dy = (pq >> 5) - (pk >> 5);
        int dx = (pq & 31) - (pk & 31);
        vsc = (dy * dy + dx * dx <= 6) ? vsc : -1e30f;
      }
      ss[t * 4 + r] = vsc;
    }
  }

  // row (per q=c) max: in-lane over 8, then across the 4 lane-groups
  float pmax = ss[0];
  #pragma unroll
  for (int j = 1; j < 8; ++j) pmax = fmaxf(pmax, ss[j]);
  pmax = fmaxf(pmax, __shfl_xor(pmax, 16));
  pmax = fmaxf(pmax, __shfl_xor(pmax, 32));

  float m_new = fmaxf(m_run, pmax);
  float fac = exp2f(m_run - m_new);
  m_run = m_new;

  float p[8];
  float psum = 0.f;
  #pragma unroll
  for (int j = 0; j < 8; ++j) { p[j] = exp2f(ss[j] - m_new); psum += p[j]; }
  psum += __shfl_xor(psum, 16);
  psum += __shfl_xor(psum, 32);
  l_run = l_run * fac + psum;

  // rescale O: O rows are q_local = 4g + r; factor lives at lane (4g+r) (its c == 4g+r)
  float fr0 = __shfl(fac, 4 * g + 0);
  float fr1 = __shfl(fac, 4 * g + 1);
  float fr2 = __shfl(fac, 4 * g + 2);
  float fr3 = __shfl(fac, 4 * g + 3);
  #pragma unroll
  for (int cc = 0; cc < 4; ++cc) {
    of[cc][0] *= fr0; of[cc][1] *= fr1; of[cc][2] *= fr2; of[cc][3] *= fr3;
  }

  // P as A-operand of O = P*V: A[m=c (q)][kslot 8g+j]; slot->kv permutation pi:
  // pi(8g+j) = kt + 4g + j (j<4) | kt + 16 + 4g + (j-4) (j>=4) -- matches p[] layout.
  f16x8 pa;
  #pragma unroll
  for (int j = 0; j < 8; ++j) pa[j] = (_Float16)p[j];

  #pragma unroll
  for (int cc = 0; cc < 4; ++cc) {
    f16x8 vb;  // B[kslot][n=c (d)] = V[pi(kslot)][16cc + c]
    #pragma unroll
    for (int j = 0; j < 8; ++j) {
      int kv = kt + ((j < 4) ? (4 * g + j) : (16 + 4 * g + (j - 4)));
      vb[j] = (_Float16)Vh[kv * DH + 16 * cc + c];
    }
    of[cc] = MFMA16(pa, vb, of[cc], 0, 0, 0);
  }
}

__global__ __launch_bounds__(64) void msa_attn(
    const float* __restrict__ q, const float* __restrict__ k,
    const float* __restrict__ v, float* __restrict__ out)
{
  const int lane = threadIdx.x;
  const int c = lane & 15, g = lane >> 4;

  // work swizzle: balance spans across CUs for both round-robin and chunked dispatch
  const int i = blockIdx.x;              // 0..2047
  const int h = i & 7;
  const int grp = (i >> 3) & 31;
  const int t3 = i >> 8;
  const int span = (t3 + grp) & 7;
  const int q_base = span * SPAN + grp * 16;

  const float* Qh = q + (size_t)h * S_LEN * DH;
  const float* Kh = k + (size_t)h * S_LEN * DH;
  const float* Vh = v + (size_t)h * S_LEN * DH;
  float* Oh = out + (size_t)h * S_LEN * DH;

  // Q as B-operand: B[k=8g+j (d)][n=c (q)]
  f16x8 qf[2];
  qf[0] = load_cvt8(Qh + (q_base + c) * DH + 8 * g);
  qf[1] = load_cvt8(Qh + (q_base + c) * DH + 8 * g + 32);

  float m_run = -1e30f, l_run = 0.f;
  f32x4 of[4] = {{0,0,0,0},{0,0,0,0},{0,0,0,0},{0,0,0,0}};

  const int qg_row = q_base + c;

  // history spans: fully valid
  const int hist_end = span * SPAN;
  for (int kt = 0; kt < hist_end; kt += 32)
    kv_tile<0>(Kh, Vh, kt, qg_row, c, g, qf, m_run, l_run, of);

  // diagonal span
  const int s0 = span * SPAN;
  if ((span & 1) == 0) {
    // causal: only kv <= q_base+15 can be valid
    const int khi = (q_base + 16 + 31) & ~31;
    for (int kt = s0; kt < khi; kt += 32)
      kv_tile<1>(Kh, Vh, kt, qg_row, c, g, qf, m_run, l_run, of);
  } else {
    // spatial: valid kv within [qi-66, qi+66]; wave rows span q_base..q_base+15
    int klo = (q_base - 66) & ~31;
    if (klo < s0) klo = s0;
    int khi = (q_base + 81 + 32) & ~31;
    const int s1 = s0 + SPAN;
    if (khi > s1) khi = s1;
    for (int kt = klo; kt < khi; kt += 32)
      kv_tile<2>(Kh, Vh, kt, qg_row, c, g, qf, m_run, l_run, of);
  }

  // epilogue: O rows q_local = 4g + r, col d = 16cc + c
  #pragma unroll
  for (int r = 0; r < 4; ++r) {
    float inv = 1.0f / __shfl(l_run, 4 * g + r);
    int row = q_base + 4 * g + r;
    #pragma unroll
    for (int cc = 0; cc < 4; ++cc)
      Oh[row * DH + 16 * cc + c] = of[cc][r] * inv;
  }
}

extern "C" void kernel_launch(void* const* d_in, const int* in_sizes, int n_in,
                              void* d_out, int out_size, void* d_ws, size_t ws_size,
                              hipStream_t stream) {
  const float* q = (const float*)d_in[0];
  const float* k = (const float*)d_in[1];
  const float* v = (const float*)d_in[2];
  float* out = (float*)d_out;
  msa_attn<<<dim3(2048), dim3(64), 0, stream>>>(q, k, v, out);
}